// Round 2
// baseline (1095.674 us; speedup 1.0000x reference)
//
#include <hip/hip_runtime.h>

// GeneralizedInteractionNet on MI355X (gfx950), bf16 MFMA formulation. R2.
//
// Reference per layer:
//   M[n,D,d]   = W[n,D,d] * h[n,d]
//   C[b,i,n,D] = sum_d Bi[b,i,d] * M[n,D,d]
//   out[b,n,D] = sum_f B0[b,f,D] * sum_i alpha[f,i,n] * C[b,i,n,D]
// Reassociated:  R[b,n,i,D] = sum_f alphaT[n,i,f]*B0[b,f,D]   (GEMM2)
//                out[b,n,D] = sum_i C[b,i,n,D]*R[b,n,i,D]     (combine)
//
// R2 changes vs R1 (which was latency-bound: 2 waves/SIMD, MfmaUtil 18%):
//  - block = one b, 4 waves split the n-loop (10 n each) -> 4x wave count
//  - B0^T staged in LDS once per block; GEMM2 B-frags via ds_read_b128
//    (replaces 64 scalar global loads per wave)
//  - layer 0 reads fp32 inputs directly (drops prep_b0 kernel + buffer)
//  - single merged prep kernel (M and alphaT)

typedef __bf16 bf16x8 __attribute__((ext_vector_type(8)));
typedef float  f32x4  __attribute__((ext_vector_type(4)));

constexpr int BATCH = 2048;
constexpr int FDIM  = 40;   // num_fields == num_subspaces
constexpr int DDIM  = 64;   // embed dim
constexpr int LAY   = 3;
constexpr int IPAD  = 48;   // i padded to 3 row tiles of 16
constexpr int FPAD  = 64;   // f (K of GEMM2) padded to 2 K-steps of 32
constexpr int NPW   = FDIM / 4;     // n per wave (4 waves/block)
constexpr int SROW  = 72;   // LDS row stride (elems): 72*2B=144B, 16B-aligned

__device__ __forceinline__ unsigned short f2bf(float f) {
  union { float f; unsigned u; } v; v.f = f;
  unsigned r = v.u + 0x7fff + ((v.u >> 16) & 1);   // round-to-nearest-even
  return (unsigned short)(r >> 16);
}

// Merged prep: M[l,n,D,d] = W*h (bf16), AT[l,n,i,f] = alpha[l,f,i,n] padded.
__global__ void prep_k(const float* __restrict__ W, const float* __restrict__ h,
                       const float* __restrict__ alpha,
                       unsigned short* __restrict__ M,
                       unsigned short* __restrict__ AT) {
  int i = blockIdx.x * blockDim.x + threadIdx.x;
  const int nM = LAY * FDIM * DDIM * DDIM;
  if (i < nM) {
    int d  = i & 63;
    int ln = i >> 12;                 // l*FDIM + n
    M[i] = f2bf(W[i] * h[ln * DDIM + d]);
    return;
  }
  int j = i - nM;
  if (j >= LAY * FDIM * IPAD * FPAD) return;
  int f  = j & 63;
  int ii = (j >> 6) % IPAD;
  int n  = (j / (IPAD * FPAD)) % FDIM;
  int l  = j / (FDIM * IPAD * FPAD);
  float v = 0.f;
  if (f < FDIM && ii < FDIM)
    v = alpha[(((size_t)l * FDIM + f) * FDIM + ii) * FDIM + n];
  AT[j] = f2bf(v);
}

// MFMA frag conventions (mfma_f32_16x16x32_bf16):
//   A-frag: A[m=lane&15][k=(lane>>4)*8+j]   B-frag: B[k=(lane>>4)*8+j][n=lane&15]
//   C/D:    col=lane&15, row=(lane>>4)*4+reg
template <bool LAYER0, bool FINAL>
__global__ __launch_bounds__(256, 5) void layer_k(
    const float* __restrict__ inF,           // fp32 inputs [B][40][64] (B0; Bi if LAYER0)
    const unsigned short* __restrict__ Bi,   // bf16 [B][40][64] (prev layer; unused if LAYER0)
    const unsigned short* __restrict__ Mt,   // [40][64][64] bf16
    const unsigned short* __restrict__ AT,   // [40][48][64] bf16, zero-padded
    void* __restrict__ outp)                 // bf16 intermediate or f32 final
{
  __shared__ unsigned short smemT[DDIM * SROW];   // B0^T: smemT[D][f], f>=40 zero

  const int tid  = threadIdx.x;
  const int lane = tid & 63;
  const int w    = tid >> 6;
  const int b    = blockIdx.x;
  const int m16  = lane & 15;
  const int q    = lane >> 4;

  const float* inb = inF + (size_t)b * (FDIM * DDIM);

  // Stage B0^T into LDS (block-cooperative, coalesced global read).
#pragma unroll
  for (int it = 0; it < 16; ++it) {
    int idx = it * 256 + tid;               // idx = f*64 + d, f in [0,64)
    int f = idx >> 6, d = idx & 63;
    unsigned short v = 0;
    if (idx < FDIM * DDIM) v = f2bf(inb[idx]);
    smemT[d * SROW + f] = v;
  }
  __syncthreads();

  // Wave-constant A-frags of Bi (rows i, k=d). Rows >=40 clamped to 39
  // (values irrelevant: multiplied by zero rows of AT via accR).
  bf16x8 aBi[3][2];
#pragma unroll
  for (int t = 0; t < 3; ++t)
#pragma unroll
    for (int ks = 0; ks < 2; ++ks) {
      int row = 16 * t + m16; if (row > FDIM - 1) row = FDIM - 1;
      if (LAYER0) {
        const float* p = inb + row * DDIM + ks * 32 + q * 8;
        float4 x0 = *reinterpret_cast<const float4*>(p);
        float4 x1 = *reinterpret_cast<const float4*>(p + 4);
        bf16x8 r;
        r[0] = __builtin_bit_cast(__bf16, f2bf(x0.x));
        r[1] = __builtin_bit_cast(__bf16, f2bf(x0.y));
        r[2] = __builtin_bit_cast(__bf16, f2bf(x0.z));
        r[3] = __builtin_bit_cast(__bf16, f2bf(x0.w));
        r[4] = __builtin_bit_cast(__bf16, f2bf(x1.x));
        r[5] = __builtin_bit_cast(__bf16, f2bf(x1.y));
        r[6] = __builtin_bit_cast(__bf16, f2bf(x1.z));
        r[7] = __builtin_bit_cast(__bf16, f2bf(x1.w));
        aBi[t][ks] = r;
      } else {
        aBi[t][ks] = *reinterpret_cast<const bf16x8*>(
            Bi + (size_t)b * (FDIM * DDIM) + row * DDIM + ks * 32 + q * 8);
      }
    }

  // Wave-constant B-frags of B0 for GEMM2: B[k=f][col=D] = smemT[D][f],
  // contiguous in f per lane -> ds_read_b128.
  bf16x8 bB0[4][2];
#pragma unroll
  for (int c = 0; c < 4; ++c)
#pragma unroll
    for (int ks = 0; ks < 2; ++ks)
      bB0[c][ks] = *reinterpret_cast<const bf16x8*>(
          smemT + (c * 16 + m16) * SROW + ks * 32 + q * 8);

  float* outF = (float*)outp;
  unsigned short* outH = (unsigned short*)outp;

  const int n0 = w * NPW;
  for (int nn = 0; nn < NPW; ++nn) {
    const int n = n0 + nn;
    const unsigned short* Mn  = Mt + n * (DDIM * DDIM);
    const unsigned short* ATn = AT + n * (IPAD * FPAD);

    bf16x8 mb[4][2], at[3][2];
#pragma unroll
    for (int c = 0; c < 4; ++c)
#pragma unroll
      for (int ks = 0; ks < 2; ++ks)
        mb[c][ks] = *reinterpret_cast<const bf16x8*>(
            Mn + (16 * c + m16) * DDIM + ks * 32 + q * 8);
#pragma unroll
    for (int t = 0; t < 3; ++t)
#pragma unroll
      for (int ks = 0; ks < 2; ++ks)
        at[t][ks] = *reinterpret_cast<const bf16x8*>(
            ATn + (16 * t + m16) * FPAD + ks * 32 + q * 8);

    float p0 = 0.f, p1 = 0.f, p2 = 0.f, p3 = 0.f;
#pragma unroll
    for (int c = 0; c < 4; ++c) {
      f32x4 accC[3], accR[3];
      const f32x4 z = {0.f, 0.f, 0.f, 0.f};
#pragma unroll
      for (int t = 0; t < 3; ++t) {
        accC[t] = __builtin_amdgcn_mfma_f32_16x16x32_bf16(aBi[t][0], mb[c][0], z, 0, 0, 0);
        accC[t] = __builtin_amdgcn_mfma_f32_16x16x32_bf16(aBi[t][1], mb[c][1], accC[t], 0, 0, 0);
        accR[t] = __builtin_amdgcn_mfma_f32_16x16x32_bf16(at[t][0], bB0[c][0], z, 0, 0, 0);
        accR[t] = __builtin_amdgcn_mfma_f32_16x16x32_bf16(at[t][1], bB0[c][1], accR[t], 0, 0, 0);
      }
      // Partial i-sum per lane (rows 16t+4q+r), butterfly over quads completes it.
      float s = 0.f;
#pragma unroll
      for (int t = 0; t < 3; ++t)
#pragma unroll
        for (int r = 0; r < 4; ++r)
          s += accC[t][r] * accR[t][r];
      s += __shfl_xor(s, 16, 64);
      s += __shfl_xor(s, 32, 64);
      if (c == 0) p0 = s; else if (c == 1) p1 = s; else if (c == 2) p2 = s; else p3 = s;
    }
    // lane stores D = 16*q + m16 = lane -> fully coalesced
    float val = (q == 0) ? p0 : (q == 1) ? p1 : (q == 2) ? p2 : p3;
    size_t off = ((size_t)b * FDIM + n) * DDIM + lane;
    if (FINAL) outF[off] = val;
    else       outH[off] = f2bf(val);
  }
}

extern "C" void kernel_launch(void* const* d_in, const int* in_sizes, int n_in,
                              void* d_out, int out_size, void* d_ws, size_t ws_size,
                              hipStream_t stream) {
  const float* inputs = (const float*)d_in[0];  // [2048,40,64]
  const float* W      = (const float*)d_in[1];  // [3,40,64,64]
  const float* alpha  = (const float*)d_in[2];  // [3,40,40,40]
  const float* h      = (const float*)d_in[3];  // [3,40,64,1]

  char* ws = (char*)d_ws;
  const size_t bufB = (size_t)BATCH * FDIM * DDIM * 2;  // bf16 intermediate
  unsigned short* Bi1 = (unsigned short*)(ws);
  unsigned short* Bi2 = (unsigned short*)(ws + bufB);
  unsigned short* Mb  = (unsigned short*)(ws + 2 * bufB);
  unsigned short* ATb = (unsigned short*)(ws + 2 * bufB + (size_t)LAY * FDIM * DDIM * DDIM * 2);

  const int nPrep = LAY * FDIM * DDIM * DDIM + LAY * FDIM * IPAD * FPAD;
  prep_k<<<(nPrep + 255) / 256, 256, 0, stream>>>(W, h, alpha, Mb, ATb);

  dim3 grid(BATCH), blk(256);
  layer_k<true,  false><<<grid, blk, 0, stream>>>(inputs, nullptr, Mb, ATb, Bi1);
  layer_k<false, false><<<grid, blk, 0, stream>>>(inputs, Bi1,
      Mb + (size_t)1 * FDIM * DDIM * DDIM, ATb + (size_t)1 * FDIM * IPAD * FPAD, Bi2);
  layer_k<false, true ><<<grid, blk, 0, stream>>>(inputs, Bi2,
      Mb + (size_t)2 * FDIM * DDIM * DDIM, ATb + (size_t)2 * FDIM * IPAD * FPAD, d_out);
}

// Round 3
// 484.842 us; speedup vs baseline: 2.2599x; 2.2599x over previous
//
#include <hip/hip_runtime.h>

// GeneralizedInteractionNet on MI355X (gfx950), bf16 MFMA formulation. R3.
//
// Reference per layer:
//   M[n,D,d]   = W[n,D,d] * h[n,d]
//   C[b,i,n,D] = sum_d Bi[b,i,d] * M[n,D,d]
//   out[b,n,D] = sum_f B0[b,f,D] * sum_i alpha[f,i,n] * C[b,i,n,D]
// Reassociated:  R[b,n,i,D] = sum_f alphaT[n,i,f]*B0[b,f,D]   (GEMM2)
//                out[b,n,D] = sum_i C[b,i,n,D]*R[b,n,i,D]     (combine)
//
// R3 vs R2: R2 spilled (launch_bounds(256,5) forced a 102-reg cap on a
// ~150-reg live set -> 1.38 GB scratch traffic/dispatch, MfmaUtil 7%).
//  - __launch_bounds__(256,4): 128-reg cap
//  - bB0 fragments read from LDS inside the c-loop (8 live regs) instead of
//    32 resident regs -> live set ~112, no spill

typedef __bf16 bf16x8 __attribute__((ext_vector_type(8)));
typedef float  f32x4  __attribute__((ext_vector_type(4)));

constexpr int BATCH = 2048;
constexpr int FDIM  = 40;   // num_fields == num_subspaces
constexpr int DDIM  = 64;   // embed dim
constexpr int LAY   = 3;
constexpr int IPAD  = 48;   // i padded to 3 row tiles of 16
constexpr int FPAD  = 64;   // f (K of GEMM2) padded to 2 K-steps of 32
constexpr int NPW   = FDIM / 4;     // n per wave (4 waves/block)
constexpr int SROW  = 72;   // LDS row stride (elems): 144B, 16B-aligned, odd*8

__device__ __forceinline__ unsigned short f2bf(float f) {
  union { float f; unsigned u; } v; v.f = f;
  unsigned r = v.u + 0x7fff + ((v.u >> 16) & 1);   // round-to-nearest-even
  return (unsigned short)(r >> 16);
}

// Merged prep: M[l,n,D,d] = W*h (bf16), AT[l,n,i,f] = alpha[l,f,i,n] padded.
__global__ void prep_k(const float* __restrict__ W, const float* __restrict__ h,
                       const float* __restrict__ alpha,
                       unsigned short* __restrict__ M,
                       unsigned short* __restrict__ AT) {
  int i = blockIdx.x * blockDim.x + threadIdx.x;
  const int nM = LAY * FDIM * DDIM * DDIM;
  if (i < nM) {
    int d  = i & 63;
    int ln = i >> 12;                 // l*FDIM + n
    M[i] = f2bf(W[i] * h[ln * DDIM + d]);
    return;
  }
  int j = i - nM;
  if (j >= LAY * FDIM * IPAD * FPAD) return;
  int f  = j & 63;
  int ii = (j >> 6) % IPAD;
  int n  = (j / (IPAD * FPAD)) % FDIM;
  int l  = j / (FDIM * IPAD * FPAD);
  float v = 0.f;
  if (f < FDIM && ii < FDIM)
    v = alpha[(((size_t)l * FDIM + f) * FDIM + ii) * FDIM + n];
  AT[j] = f2bf(v);
}

// MFMA frag conventions (mfma_f32_16x16x32_bf16):
//   A-frag: A[m=lane&15][k=(lane>>4)*8+j]   B-frag: B[k=(lane>>4)*8+j][n=lane&15]
//   C/D:    col=lane&15, row=(lane>>4)*4+reg
template <bool LAYER0, bool FINAL>
__global__ __launch_bounds__(256, 4) void layer_k(
    const float* __restrict__ inF,           // fp32 inputs [B][40][64] (B0; Bi if LAYER0)
    const unsigned short* __restrict__ Bi,   // bf16 [B][40][64] (prev layer; unused if LAYER0)
    const unsigned short* __restrict__ Mt,   // [40][64][64] bf16
    const unsigned short* __restrict__ AT,   // [40][48][64] bf16, zero-padded
    void* __restrict__ outp)                 // bf16 intermediate or f32 final
{
  __shared__ unsigned short smemT[DDIM * SROW];   // B0^T: smemT[D][f], f>=40 zero

  const int tid  = threadIdx.x;
  const int lane = tid & 63;
  const int w    = tid >> 6;
  const int b    = blockIdx.x;
  const int m16  = lane & 15;
  const int q    = lane >> 4;

  const float* inb = inF + (size_t)b * (FDIM * DDIM);

  // Stage B0^T into LDS (block-cooperative, coalesced global read).
#pragma unroll
  for (int it = 0; it < 16; ++it) {
    int idx = it * 256 + tid;               // idx = f*64 + d, f in [0,64)
    int f = idx >> 6, d = idx & 63;
    unsigned short v = 0;
    if (idx < FDIM * DDIM) v = f2bf(inb[idx]);
    smemT[d * SROW + f] = v;
  }
  __syncthreads();

  // Wave-constant A-frags of Bi (rows i, k=d). Rows >=40 clamped to 39
  // (values irrelevant: multiplied by zero rows of AT via accR).
  bf16x8 aBi[3][2];
#pragma unroll
  for (int t = 0; t < 3; ++t)
#pragma unroll
    for (int ks = 0; ks < 2; ++ks) {
      int row = 16 * t + m16; if (row > FDIM - 1) row = FDIM - 1;
      if (LAYER0) {
        const float* p = inb + row * DDIM + ks * 32 + q * 8;
        float4 x0 = *reinterpret_cast<const float4*>(p);
        float4 x1 = *reinterpret_cast<const float4*>(p + 4);
        bf16x8 r;
        r[0] = __builtin_bit_cast(__bf16, f2bf(x0.x));
        r[1] = __builtin_bit_cast(__bf16, f2bf(x0.y));
        r[2] = __builtin_bit_cast(__bf16, f2bf(x0.z));
        r[3] = __builtin_bit_cast(__bf16, f2bf(x0.w));
        r[4] = __builtin_bit_cast(__bf16, f2bf(x1.x));
        r[5] = __builtin_bit_cast(__bf16, f2bf(x1.y));
        r[6] = __builtin_bit_cast(__bf16, f2bf(x1.z));
        r[7] = __builtin_bit_cast(__bf16, f2bf(x1.w));
        aBi[t][ks] = r;
      } else {
        aBi[t][ks] = *reinterpret_cast<const bf16x8*>(
            Bi + (size_t)b * (FDIM * DDIM) + row * DDIM + ks * 32 + q * 8);
      }
    }

  float* outF = (float*)outp;
  unsigned short* outH = (unsigned short*)outp;

  const int n0 = w * NPW;
  for (int nn = 0; nn < NPW; ++nn) {
    const int n = n0 + nn;
    const unsigned short* Mn  = Mt + n * (DDIM * DDIM);
    const unsigned short* ATn = AT + n * (IPAD * FPAD);

    // Per-n operands kept in regs: M[n] (32 regs) + alphaT[n] (24 regs).
    bf16x8 mb[4][2], at[3][2];
#pragma unroll
    for (int c = 0; c < 4; ++c)
#pragma unroll
      for (int ks = 0; ks < 2; ++ks)
        mb[c][ks] = *reinterpret_cast<const bf16x8*>(
            Mn + (16 * c + m16) * DDIM + ks * 32 + q * 8);
#pragma unroll
    for (int t = 0; t < 3; ++t)
#pragma unroll
      for (int ks = 0; ks < 2; ++ks)
        at[t][ks] = *reinterpret_cast<const bf16x8*>(
            ATn + (16 * t + m16) * FPAD + ks * 32 + q * 8);

    float p0 = 0.f, p1 = 0.f, p2 = 0.f, p3 = 0.f;
#pragma unroll
    for (int c = 0; c < 4; ++c) {
      // GEMM2 B-frags of B0 read from LDS here: only 8 regs live (vs 32
      // resident) -- this plus launch_bounds(256,4) is the R3 spill fix.
      bf16x8 bB0_0 = *reinterpret_cast<const bf16x8*>(
          smemT + (c * 16 + m16) * SROW + 0 * 32 + q * 8);
      bf16x8 bB0_1 = *reinterpret_cast<const bf16x8*>(
          smemT + (c * 16 + m16) * SROW + 1 * 32 + q * 8);
      f32x4 accC[3], accR[3];
      const f32x4 z = {0.f, 0.f, 0.f, 0.f};
#pragma unroll
      for (int t = 0; t < 3; ++t) {
        accC[t] = __builtin_amdgcn_mfma_f32_16x16x32_bf16(aBi[t][0], mb[c][0], z, 0, 0, 0);
        accC[t] = __builtin_amdgcn_mfma_f32_16x16x32_bf16(aBi[t][1], mb[c][1], accC[t], 0, 0, 0);
        accR[t] = __builtin_amdgcn_mfma_f32_16x16x32_bf16(at[t][0], bB0_0, z, 0, 0, 0);
        accR[t] = __builtin_amdgcn_mfma_f32_16x16x32_bf16(at[t][1], bB0_1, accR[t], 0, 0, 0);
      }
      // Partial i-sum per lane (rows 16t+4q+r), butterfly over quads completes it.
      float s = 0.f;
#pragma unroll
      for (int t = 0; t < 3; ++t)
#pragma unroll
        for (int r = 0; r < 4; ++r)
          s += accC[t][r] * accR[t][r];
      s += __shfl_xor(s, 16, 64);
      s += __shfl_xor(s, 32, 64);
      if (c == 0) p0 = s; else if (c == 1) p1 = s; else if (c == 2) p2 = s; else p3 = s;
    }
    // lane stores D = 16*q + m16 = lane -> fully coalesced
    float val = (q == 0) ? p0 : (q == 1) ? p1 : (q == 2) ? p2 : p3;
    size_t off = ((size_t)b * FDIM + n) * DDIM + lane;
    if (FINAL) outF[off] = val;
    else       outH[off] = f2bf(val);
  }
}

extern "C" void kernel_launch(void* const* d_in, const int* in_sizes, int n_in,
                              void* d_out, int out_size, void* d_ws, size_t ws_size,
                              hipStream_t stream) {
  const float* inputs = (const float*)d_in[0];  // [2048,40,64]
  const float* W      = (const float*)d_in[1];  // [3,40,64,64]
  const float* alpha  = (const float*)d_in[2];  // [3,40,40,40]
  const float* h      = (const float*)d_in[3];  // [3,40,64,1]

  char* ws = (char*)d_ws;
  const size_t bufB = (size_t)BATCH * FDIM * DDIM * 2;  // bf16 intermediate
  unsigned short* Bi1 = (unsigned short*)(ws);
  unsigned short* Bi2 = (unsigned short*)(ws + bufB);
  unsigned short* Mb  = (unsigned short*)(ws + 2 * bufB);
  unsigned short* ATb = (unsigned short*)(ws + 2 * bufB + (size_t)LAY * FDIM * DDIM * DDIM * 2);

  const int nPrep = LAY * FDIM * DDIM * DDIM + LAY * FDIM * IPAD * FPAD;
  prep_k<<<(nPrep + 255) / 256, 256, 0, stream>>>(W, h, alpha, Mb, ATb);

  dim3 grid(BATCH), blk(256);
  layer_k<true,  false><<<grid, blk, 0, stream>>>(inputs, nullptr, Mb, ATb, Bi1);
  layer_k<false, false><<<grid, blk, 0, stream>>>(inputs, Bi1,
      Mb + (size_t)1 * FDIM * DDIM * DDIM, ATb + (size_t)1 * FDIM * IPAD * FPAD, Bi2);
  layer_k<false, true ><<<grid, blk, 0, stream>>>(inputs, Bi2,
      Mb + (size_t)2 * FDIM * DDIM * DDIM, ATb + (size_t)2 * FDIM * IPAD * FPAD, d_out);
}

// Round 4
// 337.087 us; speedup vs baseline: 3.2504x; 1.4383x over previous
//
#include <hip/hip_runtime.h>

// GeneralizedInteractionNet on MI355X (gfx950). R4: 32x32x16 MFMA, 2 b/wave,
// block-shared double-buffered LDS staging of per-n operands.
//
// Per layer:  M[n,D,d] = W[n,D,d]*h[n,d]
//   GEMM1: C[b,i,D] = sum_d Bi[b,i,d]   * M[n,D,d]     (A=Bi, B=M natural-transposed)
//   GEMM2: R[b,i,D] = sum_f AT[n,i,f]   * B0[b,f,D]    (A=alphaT, B=B0^T gather)
//   out[b,n,D] = sum_i C[b,i,D]*R[b,i,D]
// i padded 40->64 (2 row tiles of 32); f padded 40->48 (3 K-steps of 16; f>=48
// tiles skipped entirely). All padding garbage annihilated by exact zeros in AT.
//
// R4 rationale (R3 was operand-stream bound: 14 KB L2 frags per 48 MFMA,
// 1.15 GB L2/layer = 33 us floor, MfmaUtil 16%):
//  - 32x32x16: 2x FLOP per 16B/lane operand vs 16x16x32
//  - wave handles 2 b -> per-n frags amortized over 56 MFMA
//  - block (2 waves, 4 b) stages M[n] (8KB) + AT[n] (6KB) once per n via
//    global_load_lds (16B), double-buffered; L2 traffic -> 287 MB/layer
//  - bank-conflict-free frag reads: M chunk-XOR-swizzled (8-phase optimal),
//    AT rows 96 B (24 words: naturally 8-phase optimal)

typedef __bf16 bf16x8 __attribute__((ext_vector_type(8)));
typedef float  f32x16 __attribute__((ext_vector_type(16)));

constexpr int BATCH = 2048;
constexpr int FDIM  = 40;
constexpr int DDIM  = 64;
constexpr int LAY   = 3;
constexpr int IPAD  = 64;   // i padded: 2 row-tiles of 32
constexpr int FPAD  = 48;   // f padded: 3 K-steps of 16
constexpr int MB_BYTES  = DDIM * DDIM * 2;        // 8192
constexpr int AT_BYTES  = IPAD * FPAD * 2;        // 6144
constexpr int BUF_BYTES = MB_BYTES + AT_BYTES;    // 14336

__device__ __forceinline__ unsigned short f2bf(float f) {
  union { float f; unsigned u; } v; v.f = f;
  unsigned r = v.u + 0x7fff + ((v.u >> 16) & 1);   // round-to-nearest-even
  return (unsigned short)(r >> 16);
}

// async 16B global->LDS copy; LDS dest = wave-uniform base + lane*16
__device__ __forceinline__ void async16(const void* g, void* l) {
  __builtin_amdgcn_global_load_lds(
      (const __attribute__((address_space(1))) unsigned int*)g,
      (__attribute__((address_space(3))) unsigned int*)l, 16, 0, 0);
}

// Prep: M[l,n,D,d] = W*h (bf16, natural layout);
//       AT[l,n,i(64),f(48)] = alpha[l,f,i,n] zero-padded (i>=40 or f>=40 -> 0)
__global__ void prep_k(const float* __restrict__ W, const float* __restrict__ h,
                       const float* __restrict__ alpha,
                       unsigned short* __restrict__ M,
                       unsigned short* __restrict__ AT) {
  int i = blockIdx.x * blockDim.x + threadIdx.x;
  const int nM = LAY * FDIM * DDIM * DDIM;   // 491520
  if (i < nM) {
    int d  = i & 63;
    int ln = i >> 12;                         // l*FDIM + n
    M[i] = f2bf(W[i] * h[ln * DDIM + d]);
    return;
  }
  int j = i - nM;
  if (j >= LAY * FDIM * IPAD * FPAD) return;
  int f  = j % FPAD;
  int ii = (j / FPAD) % IPAD;
  int n  = (j / (FPAD * IPAD)) % FDIM;
  int l  = j / (FPAD * IPAD * FDIM);
  float v = 0.f;
  if (f < FDIM && ii < FDIM)
    v = alpha[(((size_t)l * FDIM + f) * FDIM + ii) * FDIM + n];
  AT[j] = f2bf(v);
}

// mfma_f32_32x32x16_bf16 conventions:
//   A[m=lane&31][k=8*(lane>>5)+j]  B[k=8*(lane>>5)+j][col=lane&31]
//   C/D: col=lane&31, row=(reg&3)+8*(reg>>2)+4*(lane>>5)   [HW-verified]
// (any consistent k-permutation on A and B cancels in the dot product)
template <bool LAYER0, bool FINAL>
__global__ __launch_bounds__(128, 2) void layer_k(
    const float* __restrict__ inF,           // fp32 inputs [B][40][64] (B0 always; Bi if LAYER0)
    const unsigned short* __restrict__ Bi,   // bf16 [B][40][64] prev layer (unused if LAYER0)
    const unsigned short* __restrict__ Mt,   // [40][64][64] bf16 this layer
    const unsigned short* __restrict__ ATt,  // [40][64][48] bf16 this layer, zero-padded
    void* __restrict__ outp)                 // bf16 intermediate or f32 final
{
  __shared__ __align__(16) unsigned short smem[2 * BUF_BYTES / 2];

  const int tid  = threadIdx.x;
  const int lane = tid & 63;
  const int w    = tid >> 6;        // wave in block (0,1)
  const int c    = lane & 31;       // row/col index within 32-tile
  const int h    = lane >> 5;       // k-half
  const int bb   = blockIdx.x * 4 + w * 2;   // this wave's first batch element

  // Stage M[n] (chunk-XOR-swizzled) + AT[n] (linear) into LDS buffer `buf`.
  // M swizzle: phys chunk pc of row D holds logical chunk cd = pc ^ (D&7).
  auto stage = [&](int n, int buf) {
    const unsigned short* Mn = Mt  + n * (DDIM * DDIM);
    const unsigned short* An = ATt + n * (IPAD * FPAD);
    char* base = (char*)smem + buf * BUF_BYTES;
#pragma unroll
    for (int r = 0; r < 4; ++r) {            // 4 x 2KB = 8KB of M
      int p  = r * 128 + tid;                // phys 16B-chunk index
      int D  = p >> 3, pc = p & 7;
      int cd = pc ^ (D & 7);
      async16(Mn + D * DDIM + cd * 8, base + r * 2048 + w * 1024);
    }
#pragma unroll
    for (int r = 0; r < 3; ++r)              // 3 x 2KB = 6KB of AT
      async16(An + r * 1024 + tid * 8, base + MB_BYTES + r * 2048 + w * 1024);
  };

  // ---- wave-constant register fragments (amortized over 40 n) ----
  // aBi[b2][it][ks]: GEMM1 A (rows i, k=d). Rows >=40 clamped (killed by R=0).
  bf16x8 aBi[2][2][4];
#pragma unroll
  for (int b2 = 0; b2 < 2; ++b2)
#pragma unroll
    for (int it = 0; it < 2; ++it) {
      int row = it * 32 + c; if (row > FDIM - 1) row = FDIM - 1;
#pragma unroll
      for (int ks = 0; ks < 4; ++ks) {
        if (LAYER0) {
          const float* p = inF + ((size_t)(bb + b2) * FDIM + row) * DDIM + ks * 16 + h * 8;
          bf16x8 r;
#pragma unroll
          for (int j = 0; j < 8; ++j) r[j] = __builtin_bit_cast(__bf16, f2bf(p[j]));
          aBi[b2][it][ks] = r;
        } else {
          aBi[b2][it][ks] = *reinterpret_cast<const bf16x8*>(
              Bi + ((size_t)(bb + b2) * FDIM + row) * DDIM + ks * 16 + h * 8);
        }
      }
    }

  // bB0[b2][dt][ks]: GEMM2 B = B0^T (k=f, col=D), gathered from fp32 inputs.
  // Only ks<3 (f<48); f in [40,48) clamped (killed by AT zero columns).
  bf16x8 bB0[2][2][3];
#pragma unroll
  for (int b2 = 0; b2 < 2; ++b2)
#pragma unroll
    for (int dt = 0; dt < 2; ++dt)
#pragma unroll
      for (int ks = 0; ks < 3; ++ks) {
        bf16x8 r;
#pragma unroll
        for (int j = 0; j < 8; ++j) {
          int f = ks * 16 + h * 8 + j; if (f > FDIM - 1) f = FDIM - 1;
          r[j] = __builtin_bit_cast(__bf16,
                   f2bf(inF[((size_t)(bb + b2) * FDIM + f) * DDIM + dt * 32 + c]));
        }
        bB0[b2][dt][ks] = r;
      }

  stage(0, 0);

  for (int n = 0; n < FDIM; ++n) {
    __syncthreads();                          // drains staging of buf[n&1]
    const int buf = n & 1;
    if (n + 1 < FDIM) stage(n + 1, buf ^ 1);  // async prefetch during compute

    const char* bufp = (const char*)smem + buf * BUF_BYTES;

    // mb[dt][ks]: GEMM1 B from swizzled M: addr = D*128 + (pc^ (D&7))*16
    bf16x8 mb[2][4];
#pragma unroll
    for (int dt = 0; dt < 2; ++dt)
#pragma unroll
      for (int ks = 0; ks < 4; ++ks) {
        int pc = (ks * 2 + h) ^ (c & 7);
        mb[dt][ks] = *reinterpret_cast<const bf16x8*>(
            bufp + (dt * 32 + c) * 128 + pc * 16);
      }

    float pout[2][2] = {{0.f, 0.f}, {0.f, 0.f}};   // [b2][dt]

#pragma unroll
    for (int it = 0; it < 2; ++it) {
      // at[ks]: GEMM2 A rows i=it*32+c (96B rows: bank-optimal)
      bf16x8 at[3];
#pragma unroll
      for (int ks = 0; ks < 3; ++ks)
        at[ks] = *reinterpret_cast<const bf16x8*>(
            bufp + MB_BYTES + ((it * 32 + c) * FPAD + ks * 16 + h * 8) * 2);

#pragma unroll
      for (int b2 = 0; b2 < 2; ++b2)
#pragma unroll
        for (int dt = 0; dt < 2; ++dt) {
          f32x16 accC = {0,0,0,0,0,0,0,0,0,0,0,0,0,0,0,0};
          f32x16 accR = {0,0,0,0,0,0,0,0,0,0,0,0,0,0,0,0};
#pragma unroll
          for (int ks = 0; ks < 4; ++ks)
            accC = __builtin_amdgcn_mfma_f32_32x32x16_bf16(aBi[b2][it][ks], mb[dt][ks], accC, 0, 0, 0);
#pragma unroll
          for (int ks = 0; ks < 3; ++ks)
            accR = __builtin_amdgcn_mfma_f32_32x32x16_bf16(at[ks], bB0[b2][dt][ks], accR, 0, 0, 0);
          float s = 0.f;
#pragma unroll
          for (int r = 0; r < 16; ++r) s += accC[r] * accR[r];
          pout[b2][dt] += s;
        }
    }

    // finish i-sum across lane halves; lane stores D=lane (coalesced)
#pragma unroll
    for (int b2 = 0; b2 < 2; ++b2) {
      float v0 = pout[b2][0] + __shfl_xor(pout[b2][0], 32, 64);
      float v1 = pout[b2][1] + __shfl_xor(pout[b2][1], 32, 64);
      float val = h ? v1 : v0;
      size_t off = ((size_t)(bb + b2) * FDIM + n) * DDIM + lane;
      if (FINAL) ((float*)outp)[off] = val;
      else       ((unsigned short*)outp)[off] = f2bf(val);
    }
  }
}

extern "C" void kernel_launch(void* const* d_in, const int* in_sizes, int n_in,
                              void* d_out, int out_size, void* d_ws, size_t ws_size,
                              hipStream_t stream) {
  const float* inputs = (const float*)d_in[0];  // [2048,40,64]
  const float* W      = (const float*)d_in[1];  // [3,40,64,64]
  const float* alpha  = (const float*)d_in[2];  // [3,40,40,40]
  const float* h      = (const float*)d_in[3];  // [3,40,64,1]

  char* ws = (char*)d_ws;
  const size_t bufB   = (size_t)BATCH * FDIM * DDIM * 2;          // 10.5 MB
  const size_t mElems = (size_t)LAY * FDIM * DDIM * DDIM;         // 491520
  unsigned short* Bi1 = (unsigned short*)(ws);
  unsigned short* Bi2 = (unsigned short*)(ws + bufB);
  unsigned short* Mb  = (unsigned short*)(ws + 2 * bufB);
  unsigned short* ATb = (unsigned short*)(ws + 2 * bufB + mElems * 2);

  const int nPrep = LAY * FDIM * DDIM * DDIM + LAY * FDIM * IPAD * FPAD;
  prep_k<<<(nPrep + 255) / 256, 256, 0, stream>>>(W, h, alpha, Mb, ATb);

  dim3 grid(BATCH / 4), blk(128);
  const size_t mL = (size_t)FDIM * DDIM * DDIM;   // per-layer M elems
  const size_t aL = (size_t)FDIM * IPAD * FPAD;   // per-layer AT elems
  layer_k<true,  false><<<grid, blk, 0, stream>>>(inputs, nullptr, Mb, ATb, Bi1);
  layer_k<false, false><<<grid, blk, 0, stream>>>(inputs, Bi1, Mb + mL, ATb + aL, Bi2);
  layer_k<false, true ><<<grid, blk, 0, stream>>>(inputs, Bi2, Mb + 2 * mL, ATb + 2 * aL, d_out);
}

// Round 5
// 268.485 us; speedup vs baseline: 4.0810x; 1.2555x over previous
//
#include <hip/hip_runtime.h>

// GeneralizedInteractionNet on MI355X (gfx950). R5: R4 + 2 waves/SIMD via
// n-split blocks, interleaved MFMA chains, pre-transposed B0T.
//
// Per layer:  M[n,D,d] = W[n,D,d]*h[n,d]
//   GEMM1: C[b,i,D] = sum_d Bi[b,i,d] * M[n,D,d]
//   GEMM2: R[b,i,D] = sum_f AT[n,i,f] * B0T[b,D,f]^T
//   out[b,n,D] = sum_i C[b,i,D]*R[b,i,D]
// i padded 40->64 (2 row tiles of 32); f padded 40->48 (3 K-steps of 16).
// Padding garbage annihilated by exact zeros in AT (rows i>=40, cols f>=40).
//
// R4 post-mortem: 1 wave/SIMD (Occ 9.6%) -> serial MFMA/combine chains fully
// exposed (~6k cyc per 1.3k-cyc n-iter). SQ_LDS_BANK_CONFLICT == 8.0 x
// global_load_lds count = DMA write phases, not a layout bug; ds_reads are
// at the 8-phase b128 floor already.
// R5: grid 1024 (each block 20 n, same 4 b) = 2 waves/SIMD; b2-interleaved
// MFMA chains; combine as 4 independent partial chains; B0T prepped.

typedef __bf16 bf16x8 __attribute__((ext_vector_type(8)));
typedef float  f32x16 __attribute__((ext_vector_type(16)));

constexpr int BATCH = 2048;
constexpr int FDIM  = 40;
constexpr int DDIM  = 64;
constexpr int LAY   = 3;
constexpr int IPAD  = 64;   // i padded: 2 row-tiles of 32
constexpr int FPAD  = 48;   // f padded: 3 K-steps of 16
constexpr int NHALF = 20;   // n per block (n-loop split across 2 blocks)
constexpr int MB_BYTES  = DDIM * DDIM * 2;        // 8192
constexpr int AT_BYTES  = IPAD * FPAD * 2;        // 6144
constexpr int BUF_BYTES = MB_BYTES + AT_BYTES;    // 14336

__device__ __forceinline__ unsigned short f2bf(float f) {
  union { float f; unsigned u; } v; v.f = f;
  unsigned r = v.u + 0x7fff + ((v.u >> 16) & 1);   // round-to-nearest-even
  return (unsigned short)(r >> 16);
}

// async 16B global->LDS; LDS dest = wave-uniform base + lane*16
__device__ __forceinline__ void async16(const void* g, void* l) {
  __builtin_amdgcn_global_load_lds(
      (const __attribute__((address_space(1))) unsigned int*)g,
      (__attribute__((address_space(3))) unsigned int*)l, 16, 0, 0);
}

// Prep, 4 segments:
//  M[l,n,D,d]  = W*h (bf16, natural layout)
//  AT[l,n,i64,f48] = alpha[l,f,i,n], zero-padded (i>=40 or f>=40 -> 0)
//  B0b[b,f,d]  = bf16(inputs)          (Bi operand for layer 0)
//  B0T[b,d,f48]= bf16(inputs[b,f,d]), f>=40 -> 0   (GEMM2 B operand)
__global__ void prep_k(const float* __restrict__ W, const float* __restrict__ h,
                       const float* __restrict__ alpha, const float* __restrict__ inputs,
                       unsigned short* __restrict__ M, unsigned short* __restrict__ AT,
                       unsigned short* __restrict__ B0b, unsigned short* __restrict__ B0T) {
  int i = blockIdx.x * blockDim.x + threadIdx.x;
  const int nM  = LAY * FDIM * DDIM * DDIM;   // 491520
  const int nAT = LAY * FDIM * IPAD * FPAD;   // 368640
  const int nB  = BATCH * FDIM * DDIM;        // 5242880
  const int nT  = BATCH * DDIM * FPAD;        // 6291456
  if (i < nM) {
    int d  = i & 63;
    int ln = i >> 12;
    M[i] = f2bf(W[i] * h[ln * DDIM + d]);
    return;
  }
  i -= nM;
  if (i < nAT) {
    int f  = i % FPAD;
    int ii = (i / FPAD) % IPAD;
    int n  = (i / (FPAD * IPAD)) % FDIM;
    int l  = i / (FPAD * IPAD * FDIM);
    float v = 0.f;
    if (f < FDIM && ii < FDIM)
      v = alpha[(((size_t)l * FDIM + f) * FDIM + ii) * FDIM + n];
    AT[i] = f2bf(v);
    return;
  }
  i -= nAT;
  if (i < nB) { B0b[i] = f2bf(inputs[i]); return; }
  i -= nB;
  if (i >= nT) return;
  int b   = i / (DDIM * FPAD);
  int rem = i - b * (DDIM * FPAD);
  int d   = rem / FPAD;
  int f   = rem - d * FPAD;
  B0T[i] = (f < FDIM) ? f2bf(inputs[((size_t)b * FDIM + f) * DDIM + d]) : (unsigned short)0;
}

// mfma_f32_32x32x16_bf16 conventions:
//   A[m=lane&31][k=8*(lane>>5)+j]  B[k=8*(lane>>5)+j][col=lane&31]
//   C/D: col=lane&31, row=(reg&3)+8*(reg>>2)+4*(lane>>5)   [HW-verified]
template <bool FINAL>
__global__ __launch_bounds__(128, 2) void layer_k(
    const unsigned short* __restrict__ Bi,   // bf16 [B][40][64] (prev layer / B0b)
    const unsigned short* __restrict__ B0T,  // bf16 [B][64][48]
    const unsigned short* __restrict__ Mt,   // [40][64][64] bf16
    const unsigned short* __restrict__ ATt,  // [40][64][48] bf16 zero-padded
    void* __restrict__ outp)                 // bf16 intermediate or f32 final
{
  __shared__ __align__(16) unsigned short smem[2 * BUF_BYTES / 2];

  const int tid  = threadIdx.x;
  const int lane = tid & 63;
  const int w    = tid >> 6;                  // wave in block (0,1)
  const int c    = lane & 31;
  const int h    = lane >> 5;
  const int bg   = blockIdx.x >> 1;           // b-group: 4 consecutive b
  const int nBase = (blockIdx.x & 1) * NHALF; // this block's n range
  const int bb   = bg * 4 + w * 2;            // wave's first batch element

  // Stage M[n] (chunk-XOR-swizzled) + AT[n] into LDS buffer `buf`.
  auto stage = [&](int n, int buf) {
    const unsigned short* Mn = Mt  + n * (DDIM * DDIM);
    const unsigned short* An = ATt + n * (IPAD * FPAD);
    char* base = (char*)smem + buf * BUF_BYTES;
#pragma unroll
    for (int r = 0; r < 4; ++r) {             // 8KB of M
      int p  = r * 128 + tid;
      int D  = p >> 3, pc = p & 7;
      int cd = pc ^ (D & 7);
      async16(Mn + D * DDIM + cd * 8, base + r * 2048 + w * 1024);
    }
#pragma unroll
    for (int r = 0; r < 3; ++r)               // 6KB of AT
      async16(An + r * 1024 + tid * 8, base + MB_BYTES + r * 2048 + w * 1024);
  };

  // ---- wave-constant register fragments ----
  // aBi[b2][it][ks]: GEMM1 A (rows i, k=d); rows>=40 clamped (killed by R=0 rows).
  bf16x8 aBi[2][2][4];
#pragma unroll
  for (int b2 = 0; b2 < 2; ++b2)
#pragma unroll
    for (int it = 0; it < 2; ++it) {
      int row = it * 32 + c; if (row > FDIM - 1) row = FDIM - 1;
#pragma unroll
      for (int ks = 0; ks < 4; ++ks)
        aBi[b2][it][ks] = *reinterpret_cast<const bf16x8*>(
            Bi + ((size_t)(bb + b2) * FDIM + row) * DDIM + ks * 16 + h * 8);
    }

  // bT[b2][dt][ks]: GEMM2 B = B0T[b][D][f], contiguous 16B per lane.
  bf16x8 bT[2][2][3];
#pragma unroll
  for (int b2 = 0; b2 < 2; ++b2)
#pragma unroll
    for (int dt = 0; dt < 2; ++dt)
#pragma unroll
      for (int ks = 0; ks < 3; ++ks)
        bT[b2][dt][ks] = *reinterpret_cast<const bf16x8*>(
            B0T + ((size_t)(bb + b2) * DDIM + dt * 32 + c) * FPAD + ks * 16 + h * 8);

  stage(nBase, 0);

  for (int ln = 0; ln < NHALF; ++ln) {
    const int n = nBase + ln;
    __syncthreads();                          // drains staging of buf[ln&1]
    const int buf = ln & 1;
    if (ln + 1 < NHALF) stage(n + 1, buf ^ 1);

    const char* bufp = (const char*)smem + buf * BUF_BYTES;

    // mb[dt][ks]: GEMM1 B from swizzled M: row D, phys chunk = cd ^ (D&7)
    bf16x8 mb[2][4];
#pragma unroll
    for (int dt = 0; dt < 2; ++dt)
#pragma unroll
      for (int ks = 0; ks < 4; ++ks) {
        int pc = (ks * 2 + h) ^ (c & 7);
        mb[dt][ks] = *reinterpret_cast<const bf16x8*>(
            bufp + (dt * 32 + c) * 128 + pc * 16);
      }

    float pout[2][2] = {{0.f, 0.f}, {0.f, 0.f}};   // [b2][dt]

#pragma unroll
    for (int it = 0; it < 2; ++it) {
      bf16x8 at[3];
#pragma unroll
      for (int ks = 0; ks < 3; ++ks)
        at[ks] = *reinterpret_cast<const bf16x8*>(
            bufp + MB_BYTES + ((it * 32 + c) * FPAD + ks * 16 + h * 8) * 2);

#pragma unroll
      for (int dt = 0; dt < 2; ++dt) {
        // Two independent (b2) chains interleaved -> MFMA pipe stays fed.
        f32x16 aC0 = {0,0,0,0,0,0,0,0,0,0,0,0,0,0,0,0};
        f32x16 aC1 = {0,0,0,0,0,0,0,0,0,0,0,0,0,0,0,0};
        f32x16 aR0 = {0,0,0,0,0,0,0,0,0,0,0,0,0,0,0,0};
        f32x16 aR1 = {0,0,0,0,0,0,0,0,0,0,0,0,0,0,0,0};
#pragma unroll
        for (int ks = 0; ks < 4; ++ks) {
          aC0 = __builtin_amdgcn_mfma_f32_32x32x16_bf16(aBi[0][it][ks], mb[dt][ks], aC0, 0, 0, 0);
          aC1 = __builtin_amdgcn_mfma_f32_32x32x16_bf16(aBi[1][it][ks], mb[dt][ks], aC1, 0, 0, 0);
        }
#pragma unroll
        for (int ks = 0; ks < 3; ++ks) {
          aR0 = __builtin_amdgcn_mfma_f32_32x32x16_bf16(at[ks], bT[0][dt][ks], aR0, 0, 0, 0);
          aR1 = __builtin_amdgcn_mfma_f32_32x32x16_bf16(at[ks], bT[1][dt][ks], aR1, 0, 0, 0);
        }
        // Combine: 4 independent partial chains per b2 (depth 4, not 16).
        {
          float t0 = 0.f, t1 = 0.f, t2 = 0.f, t3 = 0.f;
#pragma unroll
          for (int r = 0; r < 4; ++r) {
            t0 += aC0[r] * aR0[r];       t1 += aC0[r + 4] * aR0[r + 4];
            t2 += aC0[r + 8] * aR0[r + 8]; t3 += aC0[r + 12] * aR0[r + 12];
          }
          pout[0][dt] += (t0 + t1) + (t2 + t3);
        }
        {
          float t0 = 0.f, t1 = 0.f, t2 = 0.f, t3 = 0.f;
#pragma unroll
          for (int r = 0; r < 4; ++r) {
            t0 += aC1[r] * aR1[r];       t1 += aC1[r + 4] * aR1[r + 4];
            t2 += aC1[r + 8] * aR1[r + 8]; t3 += aC1[r + 12] * aR1[r + 12];
          }
          pout[1][dt] += (t0 + t1) + (t2 + t3);
        }
      }
    }

    // finish i-sum across lane halves; lane stores D=lane (coalesced)
#pragma unroll
    for (int b2 = 0; b2 < 2; ++b2) {
      float v0 = pout[b2][0] + __shfl_xor(pout[b2][0], 32, 64);
      float v1 = pout[b2][1] + __shfl_xor(pout[b2][1], 32, 64);
      float val = h ? v1 : v0;
      size_t off = ((size_t)(bb + b2) * FDIM + n) * DDIM + lane;
      if (FINAL) ((float*)outp)[off] = val;
      else       ((unsigned short*)outp)[off] = f2bf(val);
    }
  }
}

extern "C" void kernel_launch(void* const* d_in, const int* in_sizes, int n_in,
                              void* d_out, int out_size, void* d_ws, size_t ws_size,
                              hipStream_t stream) {
  const float* inputs = (const float*)d_in[0];  // [2048,40,64]
  const float* W      = (const float*)d_in[1];  // [3,40,64,64]
  const float* alpha  = (const float*)d_in[2];  // [3,40,40,40]
  const float* h      = (const float*)d_in[3];  // [3,40,64,1]

  char* ws = (char*)d_ws;
  const size_t S   = (size_t)BATCH * FDIM * DDIM * 2;   // 10.49 MB bf16 buffer
  const size_t ST  = (size_t)BATCH * DDIM * FPAD * 2;   // 12.58 MB B0T
  unsigned short* Bi1 = (unsigned short*)(ws);
  unsigned short* Bi2 = (unsigned short*)(ws + S);
  unsigned short* B0b = (unsigned short*)(ws + 2 * S);
  unsigned short* B0T = (unsigned short*)(ws + 3 * S);
  unsigned short* Mb  = (unsigned short*)(ws + 3 * S + ST);
  unsigned short* ATb = (unsigned short*)(ws + 3 * S + ST + (size_t)LAY * FDIM * DDIM * DDIM * 2);

  const int nPrep = LAY * FDIM * DDIM * DDIM + LAY * FDIM * IPAD * FPAD
                  + BATCH * FDIM * DDIM + BATCH * DDIM * FPAD;
  prep_k<<<(nPrep + 255) / 256, 256, 0, stream>>>(W, h, alpha, inputs, Mb, ATb, B0b, B0T);

  dim3 grid(BATCH / 4 * 2), blk(128);   // x2: n-loop split across 2 blocks
  const size_t mL = (size_t)FDIM * DDIM * DDIM;
  const size_t aL = (size_t)FDIM * IPAD * FPAD;
  layer_k<false><<<grid, blk, 0, stream>>>(B0b, B0T, Mb, ATb, Bi1);
  layer_k<false><<<grid, blk, 0, stream>>>(Bi1, B0T, Mb + mL, ATb + aL, Bi2);
  layer_k<true ><<<grid, blk, 0, stream>>>(Bi2, B0T, Mb + 2 * mL, ATb + 2 * aL, d_out);
}